// Round 1
// baseline (467.550 us; speedup 1.0000x reference)
//
#include <hip/hip_runtime.h>
#include <hip/hip_bf16.h>

#define NN 256
#define XD 256
#define ED 128

typedef __attribute__((ext_vector_type(8))) short short8;
typedef __attribute__((ext_vector_type(4))) float f32x4;

__device__ __forceinline__ unsigned short f2bf(float f) {
    unsigned u = __builtin_bit_cast(unsigned, f);
    u += 0x7FFF + ((u >> 16) & 1);
    return (unsigned short)(u >> 16);
}

// ---------------------------------------------------------------------------
// Fused edge kernel: one block per (b, i, j-half of 128 rows).
//   E1||E2 = eTile @ [Wem||Wea]  (MFMA, K=128)
//   Y      = qs*k*(E1+bem+1) + (E2+bea)   -> bf16 in LDS (m-chunks of 32 rows)
//   newE   = Y @ Weo + beo                (MFMA, K=256)
// ---------------------------------------------------------------------------
__global__ __launch_bounds__(512, 4) void fused_edge_kernel(
    const float* __restrict__ e, const float* __restrict__ Qs,
    const float* __restrict__ Kw, const short* __restrict__ WemT,
    const short* __restrict__ WeaT, const short* __restrict__ WeoT,
    const float* __restrict__ bem, const float* __restrict__ bea,
    const float* __restrict__ beo, float* __restrict__ outE)
{
    __shared__ unsigned short sE[128 * 136];   // e tile bf16, pitch 136 (pad)
    __shared__ unsigned short sY[32 * 264];    // Y chunk bf16, pitch 264 (pad)

    const int blk  = blockIdx.x;
    const int j0   = (blk & 1) * 128;
    const int i    = (blk >> 1) & 255;
    const int b    = blk >> 9;
    const int tid  = threadIdx.x;
    const int wave = tid >> 6;
    const int lane = tid & 63;
    const int quad = lane >> 4;
    const int l16  = lane & 15;

    // ---- stage e tile [128 x 128] fp32 -> bf16 LDS (contiguous 64 KB read)
    {
        const float4* src4 = (const float4*)(e + (size_t)((b * NN + i) * NN + j0) * ED);
        #pragma unroll
        for (int it = 0; it < 8; ++it) {
            int idx4 = tid + it * 512;            // 0..4095
            float4 v = src4[idx4];
            int elem = idx4 * 4;
            int row = elem >> 7;
            int col = elem & 127;
            short4 p = make_short4((short)f2bf(v.x), (short)f2bf(v.y),
                                   (short)f2bf(v.z), (short)f2bf(v.w));
            *(short4*)&sE[row * 136 + col] = p;
        }
    }
    __syncthreads();

    const float* Qrow  = Qs + (size_t)(b * NN + i) * XD;
    const float* Krows = Kw + (size_t)b * NN * XD;
    const int c0 = wave * 32;   // this wave's 32-column slice of XDIM

    for (int mc = 0; mc < 4; ++mc) {
        const int m0 = mc * 32;

        // ---- GEMM1: E1,E2 for rows [m0, m0+32), cols [c0, c0+32)
        f32x4 accE1[2][2] = {};
        f32x4 accE2[2][2] = {};
        #pragma unroll
        for (int ks = 0; ks < 4; ++ks) {
            short8 a0 = *(const short8*)&sE[(m0 + l16) * 136 + ks * 32 + quad * 8];
            short8 a1 = *(const short8*)&sE[(m0 + 16 + l16) * 136 + ks * 32 + quad * 8];
            #pragma unroll
            for (int ct = 0; ct < 2; ++ct) {
                int n = c0 + ct * 16 + l16;
                short8 b1 = *(const short8*)&WemT[n * 128 + ks * 32 + quad * 8];
                short8 b2 = *(const short8*)&WeaT[n * 128 + ks * 32 + quad * 8];
                accE1[0][ct] = __builtin_amdgcn_mfma_f32_16x16x32_bf16(a0, b1, accE1[0][ct], 0, 0, 0);
                accE1[1][ct] = __builtin_amdgcn_mfma_f32_16x16x32_bf16(a1, b1, accE1[1][ct], 0, 0, 0);
                accE2[0][ct] = __builtin_amdgcn_mfma_f32_16x16x32_bf16(a0, b2, accE2[0][ct], 0, 0, 0);
                accE2[1][ct] = __builtin_amdgcn_mfma_f32_16x16x32_bf16(a1, b2, accE2[1][ct], 0, 0, 0);
            }
        }

        // ---- combine: Y = qs*k*(E1+bem+1) + (E2+bea)  -> sY (bf16)
        #pragma unroll
        for (int mt = 0; mt < 2; ++mt) {
            #pragma unroll
            for (int ct = 0; ct < 2; ++ct) {
                int c = c0 + ct * 16 + l16;
                float qs = Qrow[c];
                float bm = bem[c] + 1.0f;
                float ba = bea[c];
                int jbase = j0 + m0 + mt * 16 + quad * 4;
                #pragma unroll
                for (int r = 0; r < 4; ++r) {
                    float kv = Krows[(size_t)(jbase + r) * XD + c];
                    float y = qs * kv * (accE1[mt][ct][r] + bm) + (accE2[mt][ct][r] + ba);
                    sY[(mt * 16 + quad * 4 + r) * 264 + c] = f2bf(y);
                }
            }
        }
        __syncthreads();

        // ---- GEMM2: newE[32 x 128] = Ychunk @ Weo ; wave owns n-tile [wave*16, +16)
        f32x4 acc2[2] = {};
        #pragma unroll
        for (int ks = 0; ks < 8; ++ks) {
            short8 bf  = *(const short8*)&WeoT[(wave * 16 + l16) * 256 + ks * 32 + quad * 8];
            short8 af0 = *(const short8*)&sY[(l16) * 264 + ks * 32 + quad * 8];
            short8 af1 = *(const short8*)&sY[(16 + l16) * 264 + ks * 32 + quad * 8];
            acc2[0] = __builtin_amdgcn_mfma_f32_16x16x32_bf16(af0, bf, acc2[0], 0, 0, 0);
            acc2[1] = __builtin_amdgcn_mfma_f32_16x16x32_bf16(af1, bf, acc2[1], 0, 0, 0);
        }
        float bo = beo[wave * 16 + l16];
        float* outBase = outE + (size_t)((b * NN + i) * NN + j0 + m0) * ED + wave * 16 + l16;
        #pragma unroll
        for (int mt = 0; mt < 2; ++mt)
            #pragma unroll
            for (int r = 0; r < 4; ++r)
                outBase[(size_t)(mt * 16 + quad * 4 + r) * ED] = acc2[mt][r] + bo;
        __syncthreads();   // protect sY before next chunk overwrites it
    }
}

// ---------------------------------------------------------------------------
// Small fp32 GEMM helper: out[rb*32 .. +32)[cc*64 .. +64) = sX @ W + bias
// sX is [32 x 256] in LDS. 256 threads: thread -> (col = cc*64 + tid%64, 8 rows).
// ---------------------------------------------------------------------------
__device__ __forceinline__ void gemm_rows32(
    const float* __restrict__ sX, const float* __restrict__ W,
    const float* __restrict__ bias, float* __restrict__ out,
    int rb, int cc, float scale, int tid)
{
    int c  = cc * 64 + (tid & 63);
    int r0 = (tid >> 6) * 8;
    float acc[8] = {0.f, 0.f, 0.f, 0.f, 0.f, 0.f, 0.f, 0.f};
    for (int k = 0; k < 256; k += 4) {
        float w0 = W[(k + 0) * 256 + c];
        float w1 = W[(k + 1) * 256 + c];
        float w2 = W[(k + 2) * 256 + c];
        float w3 = W[(k + 3) * 256 + c];
        #pragma unroll
        for (int r = 0; r < 8; ++r) {
            const float4 xv = *(const float4*)&sX[(r0 + r) * 256 + k];
            acc[r] += xv.x * w0 + xv.y * w1 + xv.z * w2 + xv.w * w3;
        }
    }
    float bb = bias[c];
    #pragma unroll
    for (int r = 0; r < 8; ++r)
        out[(size_t)(rb * 32 + r0 + r) * 256 + c] = (acc[r] + bb) * scale;
}

// Q,K,V projections. grid = 3 mats * 32 rowblocks * 4 colchunks = 384.
// Q is pre-scaled by 1/sqrt(DF).
__global__ __launch_bounds__(256) void proj_qkv_kernel(
    const float* __restrict__ x,
    const float* __restrict__ Wq, const float* __restrict__ bq,
    const float* __restrict__ Wk, const float* __restrict__ bk,
    const float* __restrict__ Wv, const float* __restrict__ bv,
    float* __restrict__ Qs, float* __restrict__ Kw, float* __restrict__ Vw)
{
    __shared__ float sX[32 * 256];
    int blk = blockIdx.x;
    int mat = blk >> 7;            // 0:Q 1:K 2:V
    int rb  = (blk & 127) >> 2;
    int cc  = blk & 3;
    const float4* xs = (const float4*)(x + (size_t)rb * 32 * 256);
    float4* sx4 = (float4*)sX;
    #pragma unroll
    for (int it = 0; it < 8; ++it) sx4[threadIdx.x + it * 256] = xs[threadIdx.x + it * 256];
    __syncthreads();
    const float* W    = mat == 0 ? Wq : (mat == 1 ? Wk : Wv);
    const float* bias = mat == 0 ? bq : (mat == 1 ? bk : bv);
    float* out        = mat == 0 ? Qs : (mat == 1 ? Kw : Vw);
    float scale       = mat == 0 ? 0.17677669529663687f : 1.0f;  // 1/sqrt(32)
    gemm_rows32(sX, W, bias, out, rb, cc, scale, threadIdx.x);
}

// newX = V @ Wxo + bxo  (softmax over i sums to 1, so weighted_V == V exactly)
__global__ __launch_bounds__(256) void proj_x_kernel(
    const float* __restrict__ Vw, const float* __restrict__ Wxo,
    const float* __restrict__ bxo, float* __restrict__ outX)
{
    __shared__ float sX[32 * 256];
    int blk = blockIdx.x;          // 128 = 32 rowblocks * 4 colchunks
    int rb  = blk >> 2;
    int cc  = blk & 3;
    const float4* xs = (const float4*)(Vw + (size_t)rb * 32 * 256);
    float4* sx4 = (float4*)sX;
    #pragma unroll
    for (int it = 0; it < 8; ++it) sx4[threadIdx.x + it * 256] = xs[threadIdx.x + it * 256];
    __syncthreads();
    gemm_rows32(sX, Wxo, bxo, outX, rb, cc, 1.0f, threadIdx.x);
}

// Transpose + bf16-convert the three edge weights into fragment-friendly
// [n][k] layouts so MFMA B-frags are contiguous 16B loads.
__global__ __launch_bounds__(256) void wconv_kernel(
    const float* __restrict__ Wem, const float* __restrict__ Wea,
    const float* __restrict__ Weo,
    short* __restrict__ WemT, short* __restrict__ WeaT, short* __restrict__ WeoT)
{
    int t = blockIdx.x * 256 + threadIdx.x;    // grid 384 -> 98304 threads
    int mat = t >> 15;
    int idx = t & 32767;
    if (mat == 0) {
        int n = idx >> 7, k = idx & 127;
        WemT[idx] = (short)f2bf(Wem[k * 256 + n]);
    } else if (mat == 1) {
        int n = idx >> 7, k = idx & 127;
        WeaT[idx] = (short)f2bf(Wea[k * 256 + n]);
    } else {
        int n = idx >> 8, k = idx & 255;
        WeoT[idx] = (short)f2bf(Weo[k * 128 + n]);
    }
}

extern "C" void kernel_launch(void* const* d_in, const int* in_sizes, int n_in,
                              void* d_out, int out_size, void* d_ws, size_t ws_size,
                              hipStream_t stream)
{
    const float* x   = (const float*)d_in[0];
    const float* e   = (const float*)d_in[1];
    const float* Wq  = (const float*)d_in[2];
    const float* bq  = (const float*)d_in[3];
    const float* Wk  = (const float*)d_in[4];
    const float* bk  = (const float*)d_in[5];
    const float* Wv  = (const float*)d_in[6];
    const float* bv  = (const float*)d_in[7];
    const float* Wem = (const float*)d_in[8];
    const float* bem = (const float*)d_in[9];
    const float* Wea = (const float*)d_in[10];
    const float* bea = (const float*)d_in[11];
    const float* Wxo = (const float*)d_in[12];
    const float* bxo = (const float*)d_in[13];
    const float* Weo = (const float*)d_in[14];
    const float* beo = (const float*)d_in[15];

    float* outX = (float*)d_out;                 // newX: 262144 f32
    float* outE = (float*)d_out + 262144;        // newE: 33554432 f32

    // workspace carve-up (3.19 MB)
    float* Qs   = (float*)d_ws;                  // [1024][256] f32 (scaled)
    float* Kw   = Qs + 262144;                   // [1024][256] f32
    float* Vw   = Kw + 262144;                   // [1024][256] f32
    short* WemT = (short*)(Vw + 262144);         // [256][128] bf16
    short* WeaT = WemT + 32768;                  // [256][128] bf16
    short* WeoT = WeaT + 32768;                  // [128][256] bf16

    hipLaunchKernelGGL(proj_qkv_kernel, dim3(384), dim3(256), 0, stream,
                       x, Wq, bq, Wk, bk, Wv, bv, Qs, Kw, Vw);
    hipLaunchKernelGGL(wconv_kernel, dim3(384), dim3(256), 0, stream,
                       Wem, Wea, Weo, WemT, WeaT, WeoT);
    hipLaunchKernelGGL(proj_x_kernel, dim3(128), dim3(256), 0, stream,
                       Vw, Wxo, bxo, outX);
    hipLaunchKernelGGL(fused_edge_kernel, dim3(2048), dim3(512), 0, stream,
                       e, Qs, Kw, WemT, WeaT, WeoT, bem, bea, beo, outE);
}

// Round 2
// 460.925 us; speedup vs baseline: 1.0144x; 1.0144x over previous
//
#include <hip/hip_runtime.h>

#define NN 256
#define XD 256
#define ED 128

typedef __attribute__((ext_vector_type(8))) short short8;
typedef __attribute__((ext_vector_type(4))) float f32x4;

__device__ __forceinline__ unsigned short f2bf(float f) {
    unsigned u = __builtin_bit_cast(unsigned, f);
    u += 0x7FFF + ((u >> 16) & 1);
    return (unsigned short)(u >> 16);
}

#define MFMA16(a, b, c) __builtin_amdgcn_mfma_f32_16x16x32_bf16(a, b, c, 0, 0, 0)

// ---------------------------------------------------------------------------
// Weight prep: transpose + bf16-convert all 7 weights to [n][k] layout.
// One block per 32x32 tile. 352 blocks total.
// ---------------------------------------------------------------------------
__global__ __launch_bounds__(256) void wprep_kernel(
    const float* __restrict__ Wq, const float* __restrict__ Wk,
    const float* __restrict__ Wv, const float* __restrict__ Wxo,
    const float* __restrict__ Wem, const float* __restrict__ Wea,
    const float* __restrict__ Weo,
    short* __restrict__ WqT, short* __restrict__ WkT,
    short* __restrict__ WvT, short* __restrict__ WxoT,
    short* __restrict__ WemT, short* __restrict__ WeaT,
    short* __restrict__ WeoT)
{
    __shared__ float sT[32][33];
    int blk = blockIdx.x;
    const float* src; short* dst; int din, dout, tile;
    if (blk < 256) {
        int m = blk >> 6; tile = blk & 63; din = 256; dout = 256;
        src = m == 0 ? Wq : (m == 1 ? Wk : (m == 2 ? Wv : Wxo));
        dst = m == 0 ? WqT : (m == 1 ? WkT : (m == 2 ? WvT : WxoT));
    } else if (blk < 320) {
        int m = (blk - 256) >> 5; tile = (blk - 256) & 31; din = 128; dout = 256;
        src = m == 0 ? Wem : Wea; dst = m == 0 ? WemT : WeaT;
    } else {
        tile = blk - 320; din = 256; dout = 128;
        src = Weo; dst = WeoT;
    }
    int ksh = (din == 256) ? 3 : 2;          // ktiles = din/32 (8 or 4)
    int kt = tile & ((1 << ksh) - 1);
    int nt = tile >> ksh;
    int c = threadIdx.x & 31, rbase = threadIdx.x >> 5;
    #pragma unroll
    for (int p = 0; p < 4; ++p) {
        int r = rbase + p * 8;
        sT[r][c] = src[(kt * 32 + r) * dout + nt * 32 + c];
    }
    __syncthreads();
    #pragma unroll
    for (int p = 0; p < 4; ++p) {
        int r = rbase + p * 8;
        dst[(nt * 32 + r) * din + kt * 32 + c] = (short)f2bf(sT[c][r]);
    }
}

// ---------------------------------------------------------------------------
// Q/K projection via MFMA. grid = 8 m-tiles x 2 mats = 16 blocks, 512 thr.
// Q stored row-major fp32 (pre-scaled by 1/sqrt(32)); K stored TRANSPOSED:
// KT[b][c][j] fp32 so the fused kernel can load K as float4 over j.
// ---------------------------------------------------------------------------
__global__ __launch_bounds__(512) void proj_qk_kernel(
    const float* __restrict__ x, const short* __restrict__ WqT,
    const short* __restrict__ WkT, const float* __restrict__ bq,
    const float* __restrict__ bk, float* __restrict__ Qs,
    float* __restrict__ KT)
{
    __shared__ unsigned short sX[128 * 264];
    const int blk = blockIdx.x;
    const int mtile = blk >> 1;   // 0..7 (128-row tile of the 1024 rows)
    const int mat   = blk & 1;    // 0: Q, 1: K
    const int tid = threadIdx.x, wave = tid >> 6, lane = tid & 63;
    const int quad = lane >> 4, l16 = lane & 15;

    {   // stage x tile fp32 -> bf16
        const float4* src4 = (const float4*)(x + (size_t)mtile * 128 * XD);
        #pragma unroll
        for (int it = 0; it < 16; ++it) {
            int idx4 = tid + it * 512;
            float4 v = src4[idx4];
            int elem = idx4 * 4, row = elem >> 8, col = elem & 255;
            short4 p = make_short4((short)f2bf(v.x), (short)f2bf(v.y),
                                   (short)f2bf(v.z), (short)f2bf(v.w));
            *(short4*)&sX[row * 264 + col] = p;
        }
    }
    __syncthreads();

    const short* WT   = mat ? WkT : WqT;
    const float* bias = mat ? bk : bq;
    const int c0 = wave * 32;

    f32x4 acc[8][2] = {};
    for (int ks = 0; ks < 8; ++ks) {
        short8 bfrag[2];
        #pragma unroll
        for (int ct = 0; ct < 2; ++ct)
            bfrag[ct] = *(const short8*)&WT[(c0 + ct * 16 + l16) * 256 + ks * 32 + quad * 8];
        #pragma unroll
        for (int mt = 0; mt < 8; ++mt) {
            short8 a = *(const short8*)&sX[(mt * 16 + l16) * 264 + ks * 32 + quad * 8];
            acc[mt][0] = MFMA16(a, bfrag[0], acc[mt][0]);
            acc[mt][1] = MFMA16(a, bfrag[1], acc[mt][1]);
        }
    }

    if (mat == 0) {
        #pragma unroll
        for (int mt = 0; mt < 8; ++mt)
            #pragma unroll
            for (int ct = 0; ct < 2; ++ct) {
                int cc = c0 + ct * 16 + l16;
                float bb = bias[cc];
                #pragma unroll
                for (int r = 0; r < 4; ++r)
                    Qs[(size_t)(mtile * 128 + mt * 16 + quad * 4 + r) * 256 + cc] =
                        (acc[mt][ct][r] + bb) * 0.17677669529663687f;
            }
    } else {
        int b = mtile >> 1, j0 = (mtile & 1) * 128;
        #pragma unroll
        for (int mt = 0; mt < 8; ++mt)
            #pragma unroll
            for (int ct = 0; ct < 2; ++ct) {
                int cc = c0 + ct * 16 + l16;
                float bb = bias[cc];
                f32x4 st;
                #pragma unroll
                for (int r = 0; r < 4; ++r) st[r] = acc[mt][ct][r] + bb;
                *(f32x4*)&KT[(size_t)(b * 256 + cc) * 256 + j0 + mt * 16 + quad * 4] = st;
            }
    }
}

// ---------------------------------------------------------------------------
// V = x@Wv + bv (bf16 in LDS), then newX = V@Wxo + bxo -> d_out.
// (softmax over i sums to 1, so weighted_V == V exactly.)
// grid = 8 m-tiles, 512 threads.
// ---------------------------------------------------------------------------
__global__ __launch_bounds__(512) void proj_vx_kernel(
    const float* __restrict__ x, const short* __restrict__ WvT,
    const float* __restrict__ bv, const short* __restrict__ WxoT,
    const float* __restrict__ bxo, float* __restrict__ outX)
{
    __shared__ unsigned short sX[128 * 264];
    __shared__ unsigned short sV[128 * 264];
    const int mtile = blockIdx.x;
    const int tid = threadIdx.x, wave = tid >> 6, lane = tid & 63;
    const int quad = lane >> 4, l16 = lane & 15;

    {
        const float4* src4 = (const float4*)(x + (size_t)mtile * 128 * XD);
        #pragma unroll
        for (int it = 0; it < 16; ++it) {
            int idx4 = tid + it * 512;
            float4 v = src4[idx4];
            int elem = idx4 * 4, row = elem >> 8, col = elem & 255;
            short4 p = make_short4((short)f2bf(v.x), (short)f2bf(v.y),
                                   (short)f2bf(v.z), (short)f2bf(v.w));
            *(short4*)&sX[row * 264 + col] = p;
        }
    }
    __syncthreads();

    const int c0 = wave * 32;
    f32x4 acc[8][2] = {};
    for (int ks = 0; ks < 8; ++ks) {
        short8 bfrag[2];
        #pragma unroll
        for (int ct = 0; ct < 2; ++ct)
            bfrag[ct] = *(const short8*)&WvT[(c0 + ct * 16 + l16) * 256 + ks * 32 + quad * 8];
        #pragma unroll
        for (int mt = 0; mt < 8; ++mt) {
            short8 a = *(const short8*)&sX[(mt * 16 + l16) * 264 + ks * 32 + quad * 8];
            acc[mt][0] = MFMA16(a, bfrag[0], acc[mt][0]);
            acc[mt][1] = MFMA16(a, bfrag[1], acc[mt][1]);
        }
    }
    #pragma unroll
    for (int mt = 0; mt < 8; ++mt)
        #pragma unroll
        for (int ct = 0; ct < 2; ++ct) {
            int cc = c0 + ct * 16 + l16;
            float bb = bv[cc];
            #pragma unroll
            for (int r = 0; r < 4; ++r)
                sV[(mt * 16 + quad * 4 + r) * 264 + cc] = f2bf(acc[mt][ct][r] + bb);
        }
    __syncthreads();

    f32x4 acc2[8][2] = {};
    for (int ks = 0; ks < 8; ++ks) {
        short8 bfrag[2];
        #pragma unroll
        for (int ct = 0; ct < 2; ++ct)
            bfrag[ct] = *(const short8*)&WxoT[(c0 + ct * 16 + l16) * 256 + ks * 32 + quad * 8];
        #pragma unroll
        for (int mt = 0; mt < 8; ++mt) {
            short8 a = *(const short8*)&sV[(mt * 16 + l16) * 264 + ks * 32 + quad * 8];
            acc2[mt][0] = MFMA16(a, bfrag[0], acc2[mt][0]);
            acc2[mt][1] = MFMA16(a, bfrag[1], acc2[mt][1]);
        }
    }
    #pragma unroll
    for (int mt = 0; mt < 8; ++mt)
        #pragma unroll
        for (int ct = 0; ct < 2; ++ct) {
            int cc = c0 + ct * 16 + l16;
            float bb = bxo[cc];
            #pragma unroll
            for (int r = 0; r < 4; ++r)
                outX[(size_t)(mtile * 128 + mt * 16 + quad * 4 + r) * 256 + cc] =
                    acc2[mt][ct][r] + bb;
        }
}

// ---------------------------------------------------------------------------
// Fused edge kernel: one block per (b, i, j-half of 128 rows).
//   E1||E2 = eTile @ [Wem||Wea]  (MFMA, K=128)
//   Y      = qs*k*(E1+bem+1) + (E2+bea)   -> bf16 in LDS (m-chunks of 32)
//   newE   = Y @ Weo + beo                (MFMA, K=256)
// K is loaded as float4 from transposed KT[b][c][j]; qs/bem/bea/beo hoisted.
// ---------------------------------------------------------------------------
__global__ __launch_bounds__(512, 4) void fused_edge_kernel(
    const float* __restrict__ e, const float* __restrict__ Qs,
    const float* __restrict__ KT, const short* __restrict__ WemT,
    const short* __restrict__ WeaT, const short* __restrict__ WeoT,
    const float* __restrict__ bem, const float* __restrict__ bea,
    const float* __restrict__ beo, float* __restrict__ outE)
{
    __shared__ unsigned short sE[128 * 136];   // e tile bf16, pitch 136
    __shared__ unsigned short sY[32 * 264];    // Y chunk bf16, pitch 264

    const int blk  = blockIdx.x;
    const int j0   = (blk & 1) * 128;
    const int i    = (blk >> 1) & 255;
    const int b    = blk >> 9;
    const int tid  = threadIdx.x;
    const int wave = tid >> 6;
    const int lane = tid & 63;
    const int quad = lane >> 4;
    const int l16  = lane & 15;

    // ---- stage e tile [128 x 128] fp32 -> bf16 LDS
    {
        const float4* src4 = (const float4*)(e + (size_t)((b * NN + i) * NN + j0) * ED);
        #pragma unroll
        for (int it = 0; it < 8; ++it) {
            int idx4 = tid + it * 512;
            float4 v = src4[idx4];
            int elem = idx4 * 4, row = elem >> 7, col = elem & 127;
            short4 p = make_short4((short)f2bf(v.x), (short)f2bf(v.y),
                                   (short)f2bf(v.z), (short)f2bf(v.w));
            *(short4*)&sE[row * 136 + col] = p;
        }
    }

    // ---- hoisted per-lane scalars (block-invariant)
    const int c0 = wave * 32;
    const float* Qrow = Qs + (size_t)(b * NN + i) * XD;
    float qsv[2], bmv[2], bav[2];
    #pragma unroll
    for (int ct = 0; ct < 2; ++ct) {
        int cc = c0 + ct * 16 + l16;
        qsv[ct] = Qrow[cc];
        bmv[ct] = bem[cc] + 1.0f;
        bav[ct] = bea[cc];
    }
    const float bo = beo[wave * 16 + l16];
    // per-lane KT base: row (b*256 + c), then + j0 + quad*4 (+ct*16*256, +m)
    const int ktbase = (b * 256 + c0 + l16) * 256 + j0 + quad * 4;

    __syncthreads();

    for (int mc = 0; mc < 4; ++mc) {
        const int m0 = mc * 32;

        // ---- GEMM1: E1,E2 for rows [m0, m0+32), cols [c0, c0+32)
        f32x4 accE1[2][2] = {};
        f32x4 accE2[2][2] = {};
        #pragma unroll
        for (int ks = 0; ks < 4; ++ks) {
            short8 a0 = *(const short8*)&sE[(m0 + l16) * 136 + ks * 32 + quad * 8];
            short8 a1 = *(const short8*)&sE[(m0 + 16 + l16) * 136 + ks * 32 + quad * 8];
            #pragma unroll
            for (int ct = 0; ct < 2; ++ct) {
                int n = c0 + ct * 16 + l16;
                short8 b1 = *(const short8*)&WemT[n * 128 + ks * 32 + quad * 8];
                short8 b2 = *(const short8*)&WeaT[n * 128 + ks * 32 + quad * 8];
                accE1[0][ct] = MFMA16(a0, b1, accE1[0][ct]);
                accE1[1][ct] = MFMA16(a1, b1, accE1[1][ct]);
                accE2[0][ct] = MFMA16(a0, b2, accE2[0][ct]);
                accE2[1][ct] = MFMA16(a1, b2, accE2[1][ct]);
            }
        }

        // ---- combine: Y = qs*k*(E1+bem+1) + (E2+bea)  -> sY (bf16)
        #pragma unroll
        for (int mt = 0; mt < 2; ++mt) {
            #pragma unroll
            for (int ct = 0; ct < 2; ++ct) {
                f32x4 kv = *(const f32x4*)&KT[ktbase + ct * 4096 + m0 + mt * 16];
                int cc = c0 + ct * 16 + l16;
                #pragma unroll
                for (int r = 0; r < 4; ++r) {
                    float y = qsv[ct] * kv[r] * (accE1[mt][ct][r] + bmv[ct])
                              + (accE2[mt][ct][r] + bav[ct]);
                    sY[(mt * 16 + quad * 4 + r) * 264 + cc] = f2bf(y);
                }
            }
        }
        __syncthreads();

        // ---- GEMM2: newE[32 x 128] = Ychunk @ Weo ; wave owns 16-col n-tile
        f32x4 acc2[2] = {};
        #pragma unroll
        for (int ks = 0; ks < 8; ++ks) {
            short8 bf  = *(const short8*)&WeoT[(wave * 16 + l16) * 256 + ks * 32 + quad * 8];
            short8 af0 = *(const short8*)&sY[(l16) * 264 + ks * 32 + quad * 8];
            short8 af1 = *(const short8*)&sY[(16 + l16) * 264 + ks * 32 + quad * 8];
            acc2[0] = MFMA16(af0, bf, acc2[0]);
            acc2[1] = MFMA16(af1, bf, acc2[1]);
        }
        float* outBase = outE + (size_t)((b * NN + i) * NN + j0 + m0) * ED + wave * 16 + l16;
        #pragma unroll
        for (int mt = 0; mt < 2; ++mt)
            #pragma unroll
            for (int r = 0; r < 4; ++r)
                outBase[(size_t)(mt * 16 + quad * 4 + r) * ED] = acc2[mt][r] + bo;
        __syncthreads();
    }
}

extern "C" void kernel_launch(void* const* d_in, const int* in_sizes, int n_in,
                              void* d_out, int out_size, void* d_ws, size_t ws_size,
                              hipStream_t stream)
{
    const float* x   = (const float*)d_in[0];
    const float* e   = (const float*)d_in[1];
    const float* Wq  = (const float*)d_in[2];
    const float* bq  = (const float*)d_in[3];
    const float* Wk  = (const float*)d_in[4];
    const float* bk  = (const float*)d_in[5];
    const float* Wv  = (const float*)d_in[6];
    const float* bv  = (const float*)d_in[7];
    const float* Wem = (const float*)d_in[8];
    const float* bem = (const float*)d_in[9];
    const float* Wea = (const float*)d_in[10];
    const float* bea = (const float*)d_in[11];
    const float* Wxo = (const float*)d_in[12];
    const float* bxo = (const float*)d_in[13];
    const float* Weo = (const float*)d_in[14];
    const float* beo = (const float*)d_in[15];

    float* outX = (float*)d_out;                 // newX: 262144 f32
    float* outE = (float*)d_out + 262144;        // newE: 33554432 f32

    // workspace carve-up (~2.8 MB)
    float* Qs   = (float*)d_ws;                  // [1024][256] f32 (scaled)
    float* KT   = Qs + 262144;                   // [4][256 c][256 j] f32
    short* WqT  = (short*)(KT + 262144);         // [256][256] bf16
    short* WkT  = WqT + 65536;
    short* WvT  = WkT + 65536;
    short* WxoT = WvT + 65536;
    short* WemT = WxoT + 65536;                  // [256][128] bf16
    short* WeaT = WemT + 32768;
    short* WeoT = WeaT + 32768;                  // [128][256] bf16

    hipLaunchKernelGGL(wprep_kernel, dim3(352), dim3(256), 0, stream,
                       Wq, Wk, Wv, Wxo, Wem, Wea, Weo,
                       WqT, WkT, WvT, WxoT, WemT, WeaT, WeoT);
    hipLaunchKernelGGL(proj_qk_kernel, dim3(16), dim3(512), 0, stream,
                       x, WqT, WkT, bq, bk, Qs, KT);
    hipLaunchKernelGGL(proj_vx_kernel, dim3(8), dim3(512), 0, stream,
                       x, WvT, bv, WxoT, bxo, outX);
    hipLaunchKernelGGL(fused_edge_kernel, dim3(2048), dim3(512), 0, stream,
                       e, Qs, KT, WemT, WeaT, WeoT, bem, bea, beo, outE);
}

// Round 3
// 366.231 us; speedup vs baseline: 1.2767x; 1.2586x over previous
//
#include <hip/hip_runtime.h>

#define NN 256
#define XD 256
#define ED 128

typedef __attribute__((ext_vector_type(8))) short short8;
typedef __attribute__((ext_vector_type(4))) float f32x4;

__device__ __forceinline__ unsigned short f2bf(float f) {
    unsigned u = __builtin_bit_cast(unsigned, f);
    u += 0x7FFF + ((u >> 16) & 1);
    return (unsigned short)(u >> 16);
}

#define MFMA16(a, b, c) __builtin_amdgcn_mfma_f32_16x16x32_bf16(a, b, c, 0, 0, 0)

// ---------------------------------------------------------------------------
// Weight prep: transpose + bf16-convert all 7 weights to [n][k] layout.
// ---------------------------------------------------------------------------
__global__ __launch_bounds__(256) void wprep_kernel(
    const float* __restrict__ Wq, const float* __restrict__ Wk,
    const float* __restrict__ Wv, const float* __restrict__ Wxo,
    const float* __restrict__ Wem, const float* __restrict__ Wea,
    const float* __restrict__ Weo,
    short* __restrict__ WqT, short* __restrict__ WkT,
    short* __restrict__ WvT, short* __restrict__ WxoT,
    short* __restrict__ WemT, short* __restrict__ WeaT,
    short* __restrict__ WeoT)
{
    __shared__ float sT[32][33];
    int blk = blockIdx.x;
    const float* src; short* dst; int din, dout, tile;
    if (blk < 256) {
        int m = blk >> 6; tile = blk & 63; din = 256; dout = 256;
        src = m == 0 ? Wq : (m == 1 ? Wk : (m == 2 ? Wv : Wxo));
        dst = m == 0 ? WqT : (m == 1 ? WkT : (m == 2 ? WvT : WxoT));
    } else if (blk < 320) {
        int m = (blk - 256) >> 5; tile = (blk - 256) & 31; din = 128; dout = 256;
        src = m == 0 ? Wem : Wea; dst = m == 0 ? WemT : WeaT;
    } else {
        tile = blk - 320; din = 256; dout = 128;
        src = Weo; dst = WeoT;
    }
    int ksh = (din == 256) ? 3 : 2;
    int kt = tile & ((1 << ksh) - 1);
    int nt = tile >> ksh;
    int c = threadIdx.x & 31, rbase = threadIdx.x >> 5;
    #pragma unroll
    for (int p = 0; p < 4; ++p) {
        int r = rbase + p * 8;
        sT[r][c] = src[(kt * 32 + r) * dout + nt * 32 + c];
    }
    __syncthreads();
    #pragma unroll
    for (int p = 0; p < 4; ++p) {
        int r = rbase + p * 8;
        dst[(nt * 32 + r) * din + kt * 32 + c] = (short)f2bf(sT[c][r]);
    }
}

// ---------------------------------------------------------------------------
// Q/K projection via MFMA. grid = 16 m-tiles (64 rows) x 2 mats = 32 blocks.
// Q row-major fp32 pre-scaled by 1/sqrt(32); K stored transposed KT[b][c][j].
// ---------------------------------------------------------------------------
__global__ __launch_bounds__(512) void proj_qk_kernel(
    const float* __restrict__ x, const short* __restrict__ WqT,
    const short* __restrict__ WkT, const float* __restrict__ bq,
    const float* __restrict__ bk, float* __restrict__ Qs,
    float* __restrict__ KT)
{
    __shared__ unsigned short sX[64 * 264];
    const int blk = blockIdx.x;
    const int mtile = blk >> 1;   // 0..15 (64-row tile of the 1024 rows)
    const int mat   = blk & 1;    // 0: Q, 1: K
    const int tid = threadIdx.x, wave = tid >> 6, lane = tid & 63;
    const int quad = lane >> 4, l16 = lane & 15;

    {   // stage x tile fp32 -> bf16
        const float4* src4 = (const float4*)(x + (size_t)mtile * 64 * XD);
        #pragma unroll
        for (int it = 0; it < 8; ++it) {
            int idx4 = tid + it * 512;
            float4 v = src4[idx4];
            int elem = idx4 * 4, row = elem >> 8, col = elem & 255;
            short4 p = make_short4((short)f2bf(v.x), (short)f2bf(v.y),
                                   (short)f2bf(v.z), (short)f2bf(v.w));
            *(short4*)&sX[row * 264 + col] = p;
        }
    }
    __syncthreads();

    const short* WT   = mat ? WkT : WqT;
    const float* bias = mat ? bk : bq;
    const int c0 = wave * 32;

    f32x4 acc[4][2] = {};
    for (int ks = 0; ks < 8; ++ks) {
        short8 bfrag[2];
        #pragma unroll
        for (int ct = 0; ct < 2; ++ct)
            bfrag[ct] = *(const short8*)&WT[(c0 + ct * 16 + l16) * 256 + ks * 32 + quad * 8];
        #pragma unroll
        for (int mt = 0; mt < 4; ++mt) {
            short8 a = *(const short8*)&sX[(mt * 16 + l16) * 264 + ks * 32 + quad * 8];
            acc[mt][0] = MFMA16(a, bfrag[0], acc[mt][0]);
            acc[mt][1] = MFMA16(a, bfrag[1], acc[mt][1]);
        }
    }

    if (mat == 0) {
        #pragma unroll
        for (int mt = 0; mt < 4; ++mt)
            #pragma unroll
            for (int ct = 0; ct < 2; ++ct) {
                int cc = c0 + ct * 16 + l16;
                float bb = bias[cc];
                #pragma unroll
                for (int r = 0; r < 4; ++r)
                    Qs[(size_t)(mtile * 64 + mt * 16 + quad * 4 + r) * 256 + cc] =
                        (acc[mt][ct][r] + bb) * 0.17677669529663687f;
            }
    } else {
        int b = mtile >> 2, j0p = (mtile & 3) * 64;
        #pragma unroll
        for (int mt = 0; mt < 4; ++mt)
            #pragma unroll
            for (int ct = 0; ct < 2; ++ct) {
                int cc = c0 + ct * 16 + l16;
                float bb = bias[cc];
                f32x4 st;
                #pragma unroll
                for (int r = 0; r < 4; ++r) st[r] = acc[mt][ct][r] + bb;
                *(f32x4*)&KT[(size_t)(b * 256 + cc) * 256 + j0p + mt * 16 + quad * 4] = st;
            }
    }
}

// ---------------------------------------------------------------------------
// V = x@Wv + bv (bf16 in LDS), then newX = V@Wxo + bxo.
// grid = 16 m-tiles (64 rows), 512 threads.
// ---------------------------------------------------------------------------
__global__ __launch_bounds__(512) void proj_vx_kernel(
    const float* __restrict__ x, const short* __restrict__ WvT,
    const float* __restrict__ bv, const short* __restrict__ WxoT,
    const float* __restrict__ bxo, float* __restrict__ outX)
{
    __shared__ unsigned short sX[64 * 264];
    __shared__ unsigned short sV[64 * 264];
    const int mtile = blockIdx.x;
    const int tid = threadIdx.x, wave = tid >> 6, lane = tid & 63;
    const int quad = lane >> 4, l16 = lane & 15;

    {
        const float4* src4 = (const float4*)(x + (size_t)mtile * 64 * XD);
        #pragma unroll
        for (int it = 0; it < 8; ++it) {
            int idx4 = tid + it * 512;
            float4 v = src4[idx4];
            int elem = idx4 * 4, row = elem >> 8, col = elem & 255;
            short4 p = make_short4((short)f2bf(v.x), (short)f2bf(v.y),
                                   (short)f2bf(v.z), (short)f2bf(v.w));
            *(short4*)&sX[row * 264 + col] = p;
        }
    }
    __syncthreads();

    const int c0 = wave * 32;
    f32x4 acc[4][2] = {};
    for (int ks = 0; ks < 8; ++ks) {
        short8 bfrag[2];
        #pragma unroll
        for (int ct = 0; ct < 2; ++ct)
            bfrag[ct] = *(const short8*)&WvT[(c0 + ct * 16 + l16) * 256 + ks * 32 + quad * 8];
        #pragma unroll
        for (int mt = 0; mt < 4; ++mt) {
            short8 a = *(const short8*)&sX[(mt * 16 + l16) * 264 + ks * 32 + quad * 8];
            acc[mt][0] = MFMA16(a, bfrag[0], acc[mt][0]);
            acc[mt][1] = MFMA16(a, bfrag[1], acc[mt][1]);
        }
    }
    #pragma unroll
    for (int mt = 0; mt < 4; ++mt)
        #pragma unroll
        for (int ct = 0; ct < 2; ++ct) {
            int cc = c0 + ct * 16 + l16;
            float bb = bv[cc];
            #pragma unroll
            for (int r = 0; r < 4; ++r)
                sV[(mt * 16 + quad * 4 + r) * 264 + cc] = f2bf(acc[mt][ct][r] + bb);
        }
    __syncthreads();

    f32x4 acc2[4][2] = {};
    for (int ks = 0; ks < 8; ++ks) {
        short8 bfrag[2];
        #pragma unroll
        for (int ct = 0; ct < 2; ++ct)
            bfrag[ct] = *(const short8*)&WxoT[(c0 + ct * 16 + l16) * 256 + ks * 32 + quad * 8];
        #pragma unroll
        for (int mt = 0; mt < 4; ++mt) {
            short8 a = *(const short8*)&sV[(mt * 16 + l16) * 264 + ks * 32 + quad * 8];
            acc2[mt][0] = MFMA16(a, bfrag[0], acc2[mt][0]);
            acc2[mt][1] = MFMA16(a, bfrag[1], acc2[mt][1]);
        }
    }
    #pragma unroll
    for (int mt = 0; mt < 4; ++mt)
        #pragma unroll
        for (int ct = 0; ct < 2; ++ct) {
            int cc = c0 + ct * 16 + l16;
            float bb = bxo[cc];
            #pragma unroll
            for (int r = 0; r < 4; ++r)
                outX[(size_t)(mtile * 64 + mt * 16 + quad * 4 + r) * 256 + cc] =
                    acc2[mt][ct][r] + bb;
        }
}

// ---------------------------------------------------------------------------
// Fused edge kernel v3: block = 256 thr (4 waves), tile = 64 j-rows.
// Pass-outer structure keeps GEMM1 B-frags register-resident; 16-row m-chunks
// keep accumulators at 32 AGPRs; only 2 barriers per block; 3 blocks/CU.
// ---------------------------------------------------------------------------
__global__ __launch_bounds__(256, 3) void fused_edge_kernel(
    const float* __restrict__ e, const float* __restrict__ Qs,
    const float* __restrict__ KT, const short* __restrict__ WemT,
    const short* __restrict__ WeaT, const short* __restrict__ WeoT,
    const float* __restrict__ bem, const float* __restrict__ bea,
    const float* __restrict__ beo, float* __restrict__ outE)
{
    __shared__ unsigned short sE[64 * 140];   // e tile bf16, pitch 140
    __shared__ unsigned short sY[64 * 268];   // Y tile bf16, pitch 268

    const int blk  = blockIdx.x;              // 4096 blocks
    const int jq   = blk & 3;
    const int i    = (blk >> 2) & 255;
    const int b    = blk >> 10;
    const int j0   = jq * 64;
    const int tid  = threadIdx.x;
    const int wave = tid >> 6;
    const int lane = tid & 63;
    const int quad = lane >> 4;
    const int l16  = lane & 15;

    // ---- stage e tile [64 x 128] fp32 -> bf16 LDS
    {
        const float4* src4 = (const float4*)(e + (size_t)((b * NN + i) * NN + j0) * ED);
        #pragma unroll
        for (int it = 0; it < 8; ++it) {
            int idx4 = tid + it * 256;
            float4 v = src4[idx4];
            int elem = idx4 * 4, row = elem >> 7, col = elem & 127;
            short4 p = make_short4((short)f2bf(v.x), (short)f2bf(v.y),
                                   (short)f2bf(v.z), (short)f2bf(v.w));
            *(short4*)&sE[row * 140 + col] = p;
        }
    }

    const float* Qrow = Qs + (size_t)(b * NN + i) * XD;
    float bo[2];
    #pragma unroll
    for (int ct = 0; ct < 2; ++ct) bo[ct] = beo[wave * 32 + ct * 16 + l16];

    __syncthreads();

    // ---- GEMM1 + combine, pass-outer over column halves
    #pragma unroll
    for (int p = 0; p < 2; ++p) {
        const int c0 = wave * 32 + p * 128;
        float qsv[2], bmv[2], bav[2];
        int ktA[2];
        #pragma unroll
        for (int ct = 0; ct < 2; ++ct) {
            int cc = c0 + ct * 16 + l16;
            qsv[ct] = Qrow[cc];
            bmv[ct] = bem[cc] + 1.0f;
            bav[ct] = bea[cc];
            ktA[ct] = (b * 256 + cc) * 256 + j0 + quad * 4;
        }
        // register-resident B fragments for this pass (reused by all 4 m-chunks)
        short8 B1[4][2], B2[4][2];
        #pragma unroll
        for (int ks = 0; ks < 4; ++ks)
            #pragma unroll
            for (int ct = 0; ct < 2; ++ct) {
                int n = c0 + ct * 16 + l16;
                B1[ks][ct] = *(const short8*)&WemT[n * 128 + ks * 32 + quad * 8];
                B2[ks][ct] = *(const short8*)&WeaT[n * 128 + ks * 32 + quad * 8];
            }
        #pragma unroll
        for (int mc = 0; mc < 4; ++mc) {
            const int m0 = mc * 16;
            f32x4 aE1[2] = {}, aE2[2] = {};
            #pragma unroll
            for (int ks = 0; ks < 4; ++ks) {
                short8 a = *(const short8*)&sE[(m0 + l16) * 140 + ks * 32 + quad * 8];
                aE1[0] = MFMA16(a, B1[ks][0], aE1[0]);
                aE1[1] = MFMA16(a, B1[ks][1], aE1[1]);
                aE2[0] = MFMA16(a, B2[ks][0], aE2[0]);
                aE2[1] = MFMA16(a, B2[ks][1], aE2[1]);
            }
            #pragma unroll
            for (int ct = 0; ct < 2; ++ct) {
                f32x4 kv = *(const f32x4*)&KT[ktA[ct] + m0];
                int cc = c0 + ct * 16 + l16;
                #pragma unroll
                for (int r = 0; r < 4; ++r) {
                    float y = qsv[ct] * kv[r] * (aE1[ct][r] + bmv[ct])
                              + (aE2[ct][r] + bav[ct]);
                    sY[(m0 + quad * 4 + r) * 268 + cc] = f2bf(y);
                }
            }
        }
    }
    __syncthreads();

    // ---- GEMM2: newE[64 x 128] = Y @ Weo ; wave owns 32-col n-slice
    short8 B3[8][2];
    #pragma unroll
    for (int ks = 0; ks < 8; ++ks)
        #pragma unroll
        for (int ct = 0; ct < 2; ++ct)
            B3[ks][ct] = *(const short8*)&WeoT[(wave * 32 + ct * 16 + l16) * 256 + ks * 32 + quad * 8];
    f32x4 acc2[4][2] = {};
    #pragma unroll
    for (int ks = 0; ks < 8; ++ks) {
        #pragma unroll
        for (int mt = 0; mt < 4; ++mt) {
            short8 a = *(const short8*)&sY[(mt * 16 + l16) * 268 + ks * 32 + quad * 8];
            acc2[mt][0] = MFMA16(a, B3[ks][0], acc2[mt][0]);
            acc2[mt][1] = MFMA16(a, B3[ks][1], acc2[mt][1]);
        }
    }
    float* outBase = outE + (size_t)((b * NN + i) * NN + j0) * ED;
    #pragma unroll
    for (int mt = 0; mt < 4; ++mt)
        #pragma unroll
        for (int ct = 0; ct < 2; ++ct) {
            int col = wave * 32 + ct * 16 + l16;
            #pragma unroll
            for (int r = 0; r < 4; ++r)
                outBase[(size_t)(mt * 16 + quad * 4 + r) * ED + col] = acc2[mt][ct][r] + bo[ct];
        }
}

extern "C" void kernel_launch(void* const* d_in, const int* in_sizes, int n_in,
                              void* d_out, int out_size, void* d_ws, size_t ws_size,
                              hipStream_t stream)
{
    const float* x   = (const float*)d_in[0];
    const float* e   = (const float*)d_in[1];
    const float* Wq  = (const float*)d_in[2];
    const float* bq  = (const float*)d_in[3];
    const float* Wk  = (const float*)d_in[4];
    const float* bk  = (const float*)d_in[5];
    const float* Wv  = (const float*)d_in[6];
    const float* bv  = (const float*)d_in[7];
    const float* Wem = (const float*)d_in[8];
    const float* bem = (const float*)d_in[9];
    const float* Wea = (const float*)d_in[10];
    const float* bea = (const float*)d_in[11];
    const float* Wxo = (const float*)d_in[12];
    const float* bxo = (const float*)d_in[13];
    const float* Weo = (const float*)d_in[14];
    const float* beo = (const float*)d_in[15];

    float* outX = (float*)d_out;                 // newX: 262144 f32
    float* outE = (float*)d_out + 262144;        // newE: 33554432 f32

    float* Qs   = (float*)d_ws;                  // [1024][256] f32 (scaled)
    float* KT   = Qs + 262144;                   // [4][256 c][256 j] f32
    short* WqT  = (short*)(KT + 262144);         // [256][256] bf16
    short* WkT  = WqT + 65536;
    short* WvT  = WkT + 65536;
    short* WxoT = WvT + 65536;
    short* WemT = WxoT + 65536;                  // [256][128] bf16
    short* WeaT = WemT + 32768;
    short* WeoT = WeaT + 32768;                  // [128][256] bf16

    hipLaunchKernelGGL(wprep_kernel, dim3(352), dim3(256), 0, stream,
                       Wq, Wk, Wv, Wxo, Wem, Wea, Weo,
                       WqT, WkT, WvT, WxoT, WemT, WeaT, WeoT);
    hipLaunchKernelGGL(proj_qk_kernel, dim3(32), dim3(512), 0, stream,
                       x, WqT, WkT, bq, bk, Qs, KT);
    hipLaunchKernelGGL(proj_vx_kernel, dim3(16), dim3(512), 0, stream,
                       x, WvT, bv, WxoT, bxo, outX);
    hipLaunchKernelGGL(fused_edge_kernel, dim3(4096), dim3(256), 0, stream,
                       e, Qs, KT, WemT, WeaT, WeoT, bem, bea, beo, outE);
}